// Round 11
// baseline (2424.426 us; speedup 1.0000x reference)
//
#include <hip/hip_runtime.h>
#include <hip/hip_bf16.h>

// Problem constants (from reference)
#define B_TOT 16384
#define DD    384
#define HH    1024
#define DRR   512
#define DMM   1152
#define SS    6     // 1 + KP + KN
#define KPP   3
#define KNN   2

typedef unsigned short ushort_t;
typedef __bf16 bf16x8 __attribute__((ext_vector_type(8)));
typedef float  f32x4  __attribute__((ext_vector_type(4)));

// ---------------------------------------------------------------- helpers
__device__ __forceinline__ float fexp2(float x) { return __builtin_amdgcn_exp2f(x); }
__device__ __forceinline__ float frcp(float x)  { return __builtin_amdgcn_rcpf(x); }
__device__ __forceinline__ float sigmoid_f(float x) {
    return frcp(1.f + fexp2(-1.4426950408889634f * x));
}
__device__ __forceinline__ float gelu_f(float x) {
    float z = 0.7978845608028654f * x * (1.f + 0.044715f * x * x);
    return x * frcp(1.f + fexp2(-2.885390081777927f * z));
}
__device__ __forceinline__ float wave_red_sum(float v) {
    #pragma unroll
    for (int off = 32; off; off >>= 1) v += __shfl_xor(v, off);
    return v;
}
__device__ __forceinline__ ushort_t f2bf(float v) {
    __hip_bfloat16 h = __float2bfloat16(v);
    return *reinterpret_cast<ushort_t*>(&h);
}
__device__ __forceinline__ float bf2f(ushort_t u) {
    unsigned int x = ((unsigned int)u) << 16;
    return __uint_as_float(x);
}
// async global->LDS, 16B per lane
__device__ __forceinline__ void g2l16(const ushort_t* g, ushort_t* l) {
    __builtin_amdgcn_global_load_lds(
        (const __attribute__((address_space(1))) void*)g,
        (__attribute__((address_space(3))) void*)l, 16, 0, 0);
}
// XCD-aware bijective block swizzle
__device__ __forceinline__ void swz_xy(int& bx, int& by) {
    const int nx = gridDim.x;
    const int nwg = nx * gridDim.y;
    const int h = by * nx + bx;
    const int q = nwg >> 3, r = nwg & 7;
    const int xcd = h & 7, lo = h >> 3;
    const int lin = (xcd < r) ? (xcd * (q + 1) + lo)
                              : (r * (q + 1) + (xcd - r) * q + lo);
    bx = lin % nx;
    by = lin / nx;
}

// ---------------------------------------------------------------- MFMA GEMM
// m97 single-buffer structure, 32 KiB LDS -> 4 blocks/CU (round-9 proven).
template<int EPI, bool ACCUM>
__global__ __launch_bounds__(256, 4)
void bgemm(const ushort_t* __restrict__ A, const ushort_t* __restrict__ WT,
           const float* __restrict__ bias, const ushort_t* __restrict__ X2,
           float* __restrict__ C, ushort_t* __restrict__ Ch, ushort_t* __restrict__ Ch2,
           int M, int N, int K)
{
    __shared__ ushort_t sm[16384];   // 32 KiB

    int bx = blockIdx.x, by = blockIdx.y;
    swz_xy(bx, by);
    const int tid = threadIdx.x;
    const int l = tid & 63, w = tid >> 6;
    const int wr = w >> 1, wc = w & 1;
    const int lr = l & 15, hi = l >> 4;
    const int row0 = by * 128, col0 = bx * 128;

    const int lrw = l >> 3;
    const int lch = (l & 7) ^ (lrw & 7);
    const ushort_t* As[4]; const ushort_t* Bs[4]; int lo_[4];
    #pragma unroll
    for (int i = 0; i < 4; ++i) {
        const int g = w * 4 + i;
        As[i] = A  + (size_t)(row0 + g*8 + lrw) * K + lch * 8;
        Bs[i] = WT + (size_t)(col0 + g*8 + lrw) * K + lch * 8;
        lo_[i] = g * 512;
    }
    const int ko[2] = {(hi*8) ^ ((lr&7)*8), (32 + hi*8) ^ ((lr&7)*8)};

    f32x4 acc[4][4] = {};
    const int NT = K >> 6;

    #pragma unroll
    for (int i = 0; i < 4; ++i) {
        g2l16(As[i], &sm[lo_[i]]);
        g2l16(Bs[i], &sm[8192 + lo_[i]]);
    }
    for (int t = 0; t < NT; ++t) {
        __syncthreads();                       // drains vmcnt: tile t ready
        #pragma unroll
        for (int ks = 0; ks < 2; ++ks) {
            bf16x8 af[4], bfr[4];
            #pragma unroll
            for (int m = 0; m < 4; ++m)
                af[m] = *(const bf16x8*)&sm[(wr*64 + m*16 + lr)*64 + ko[ks]];
            #pragma unroll
            for (int n = 0; n < 4; ++n)
                bfr[n] = *(const bf16x8*)&sm[8192 + (wc*64 + n*16 + lr)*64 + ko[ks]];
            #pragma unroll
            for (int m = 0; m < 4; ++m)
                #pragma unroll
                for (int n = 0; n < 4; ++n)
                    acc[m][n] = __builtin_amdgcn_mfma_f32_16x16x32_bf16(
                        af[m], bfr[n], acc[m][n], 0, 0, 0);
        }
        __syncthreads();                       // all waves done reading LDS
        if (t + 1 < NT) {
            #pragma unroll
            for (int i = 0; i < 4; ++i) {
                g2l16(As[i] + (size_t)(t+1)*64, &sm[lo_[i]]);
                g2l16(Bs[i] + (size_t)(t+1)*64, &sm[8192 + lo_[i]]);
            }
        }
    }

    // epilogue: C/D frag mapping col = l&15, row = (l>>4)*4 + j
    const bool BF = (EPI == 7) || (Ch != nullptr);
    #pragma unroll
    for (int m = 0; m < 4; ++m) {
        #pragma unroll
        for (int n = 0; n < 4; ++n) {
            const int r0 = row0 + wr*64 + m*16 + hi*4;
            const int c  = col0 + wc*64 + n*16 + lr;
            const float bv = bias ? bias[c] : 0.f;
            const int rl0 = wr*64 + m*16 + hi*4;
            const int cl  = wc*64 + n*16 + lr;
            #pragma unroll
            for (int j = 0; j < 4; ++j) {
                const int r = r0 + j;
                float v = acc[m][n][j] + bv;
                if (EPI == 1) v = fmaxf(v, 0.f);
                if (EPI == 4) v = v - bf2f(X2[(size_t)r * N + c]);
                if (ACCUM)    v += C[(size_t)r * N + c];
                if (C) C[(size_t)r * N + c] = v;
                if (BF) {
                    float ov = (EPI == 7 && c >= 512) ? gelu_f(v) : v;
                    const int rl = rl0 + j;
                    sm[rl*128 + ((((cl>>3) ^ (rl & 7))) << 3) + (cl & 7)] = f2bf(ov);
                }
            }
        }
    }
    if (BF) {
        __syncthreads();
        const int er = tid >> 1, ec = (tid & 1) * 64;
        ushort_t* dst; int nn, dc0;
        if (EPI == 7) {
            nn = 512;
            if (col0 < 512) { dst = Ch;  dc0 = col0; }
            else            { dst = Ch2; dc0 = col0 - 512; }
        } else { dst = Ch; nn = N; dc0 = col0; }
        ushort_t* gp = dst + (size_t)(row0 + er) * nn + dc0 + ec;
        #pragma unroll
        for (int qq = 0; qq < 8; ++qq) {
            const int q = (ec >> 3) + qq;
            const uint4 vv = *(const uint4*)&sm[er*128 + ((q ^ (er & 7)) << 3)];
            *(uint4*)(gp + qq*8) = vv;
        }
    }
}

// ---------------------------------------------------------------- dual-B GEMM
// Round-9 structure (B via global_load_lds, single-buffer 32 KiB), but
// __launch_bounds__(256,5): VGPR is only 64, LDS allows 5 blocks/CU — the
// previous (256,4) declaration was the occupancy cap, not a HW resource.
template<bool LOGITS>
__global__ __launch_bounds__(256, 5)
void dual_k(const ushort_t* __restrict__ A, const ushort_t* __restrict__ W1T,
            const ushort_t* __restrict__ W2T, ushort_t* __restrict__ Ch,
            float* __restrict__ LP, const float* __restrict__ wproj,
            int M, int N, int K)
{
    __shared__ ushort_t sm[16384];

    int bx = blockIdx.x, by = blockIdx.y;
    swz_xy(bx, by);
    const int tid = threadIdx.x;
    const int l = tid & 63, w = tid >> 6;
    const int wr = w >> 1, wc = w & 1;
    const int lr = l & 15, hi = l >> 4;
    const int row0 = by * 128, col0 = bx * 64;

    const int lrw = l >> 3;
    const int lch = (l & 7) ^ (lrw & 7);
    const ushort_t* As[4]; int loA[4];
    #pragma unroll
    for (int i = 0; i < 4; ++i) {
        const int g = w * 4 + i;
        As[i] = A + (size_t)(row0 + g*8 + lrw) * K + lch * 8;
        loA[i] = g * 512;
    }
    const ushort_t* Gs[2]; const ushort_t* Vs[2]; int loB[2];
    #pragma unroll
    for (int i = 0; i < 2; ++i) {
        const int g = w * 2 + i;
        Gs[i] = W1T + (size_t)(col0 + g*8 + lrw) * K + lch * 8;
        Vs[i] = W2T + (size_t)(col0 + g*8 + lrw) * K + lch * 8;
        loB[i] = g * 512;
    }
    const int ko[2] = {(hi*8) ^ ((lr&7)*8), (32 + hi*8) ^ ((lr&7)*8)};

    f32x4 ag[4][2] = {}, av[4][2] = {};
    const int NT = K >> 6;

    #pragma unroll
    for (int i = 0; i < 4; ++i) g2l16(As[i], &sm[loA[i]]);
    #pragma unroll
    for (int i = 0; i < 2; ++i) {
        g2l16(Gs[i], &sm[8192  + loB[i]]);
        g2l16(Vs[i], &sm[12288 + loB[i]]);
    }
    for (int t = 0; t < NT; ++t) {
        __syncthreads();
        #pragma unroll
        for (int ks = 0; ks < 2; ++ks) {
            bf16x8 af[4], bg[2], bv[2];
            #pragma unroll
            for (int m = 0; m < 4; ++m)
                af[m] = *(const bf16x8*)&sm[(wr*64 + m*16 + lr)*64 + ko[ks]];
            #pragma unroll
            for (int n = 0; n < 2; ++n) {
                bg[n] = *(const bf16x8*)&sm[8192  + (wc*32 + n*16 + lr)*64 + ko[ks]];
                bv[n] = *(const bf16x8*)&sm[12288 + (wc*32 + n*16 + lr)*64 + ko[ks]];
            }
            #pragma unroll
            for (int m = 0; m < 4; ++m)
                #pragma unroll
                for (int n = 0; n < 2; ++n) {
                    ag[m][n] = __builtin_amdgcn_mfma_f32_16x16x32_bf16(af[m], bg[n], ag[m][n], 0, 0, 0);
                    av[m][n] = __builtin_amdgcn_mfma_f32_16x16x32_bf16(af[m], bv[n], av[m][n], 0, 0, 0);
                }
        }
        __syncthreads();
        if (t + 1 < NT) {
            #pragma unroll
            for (int i = 0; i < 4; ++i)
                g2l16(As[i] + (size_t)(t+1)*64, &sm[loA[i]]);
            #pragma unroll
            for (int i = 0; i < 2; ++i) {
                g2l16(Gs[i] + (size_t)(t+1)*64, &sm[8192  + loB[i]]);
                g2l16(Vs[i] + (size_t)(t+1)*64, &sm[12288 + loB[i]]);
            }
        }
    }

    if (!LOGITS) {
        #pragma unroll
        for (int m = 0; m < 4; ++m)
            #pragma unroll
            for (int n = 0; n < 2; ++n) {
                const int cl = wc*32 + n*16 + lr;
                #pragma unroll
                for (int j = 0; j < 4; ++j) {
                    const int rl = wr*64 + m*16 + hi*4 + j;
                    sm[rl*64 + (((cl>>3) ^ (rl & 7)) << 3) + (cl & 7)] =
                        f2bf(gelu_f(ag[m][n][j]) * av[m][n][j]);
                }
            }
        __syncthreads();
        const int er = tid >> 1, ec = (tid & 1) * 32;
        ushort_t* gp = Ch + (size_t)(row0 + er) * N + col0 + ec;
        #pragma unroll
        for (int qq = 0; qq < 4; ++qq) {
            const int q = (ec >> 3) + qq;
            const uint4 vv = *(const uint4*)&sm[er*64 + ((q ^ (er & 7)) << 3)];
            *(uint4*)(gp + qq*8) = vv;
        }
    } else {
        float wp[2];
        #pragma unroll
        for (int n = 0; n < 2; ++n) wp[n] = wproj[col0 + wc*32 + n*16 + lr];
        float* red = (float*)sm;   // [128][2]
        #pragma unroll
        for (int m = 0; m < 4; ++m) {
            #pragma unroll
            for (int j = 0; j < 4; ++j) {
                float s = 0.f;
                #pragma unroll
                for (int n = 0; n < 2; ++n)
                    s += gelu_f(ag[m][n][j]) * av[m][n][j] * wp[n];
                s += __shfl_xor(s, 1);
                s += __shfl_xor(s, 2);
                s += __shfl_xor(s, 4);
                s += __shfl_xor(s, 8);
                if (lr == 0) red[(wr*64 + m*16 + hi*4 + j) * 2 + wc] = s;
            }
        }
        __syncthreads();
        if (tid < 128)
            LP[(size_t)(row0 + tid) * 6 + bx] = red[tid*2] + red[tid*2 + 1];
    }
}

// ---------------------------------------------------------------- RG-LRU recurrence
__global__ __launch_bounds__(256, 8)
void rec_k(ushort_t* __restrict__ u, const ushort_t* __restrict__ gate,
           const ushort_t* __restrict__ ri, const float* __restrict__ a2,
           int Bc)
{
    const int g = blockIdx.x * 256 + threadIdx.x;   // < Bc*64
    const int b = g >> 6, c8 = (g & 63) << 3;
    float a2v[8];
    *(float4*)&a2v[0] = *(const float4*)&a2[c8];
    *(float4*)&a2v[4] = *(const float4*)&a2[c8 + 4];
    float h[8] = {};
    for (int t = 0; t < SS; ++t) {
        const size_t row = (size_t)t * Bc + b;
        uint4 uw = *(const uint4*)&u[row * DRR + c8];
        uint4 rw = *(const uint4*)&ri[row * 1024 + c8];
        uint4 iw = *(const uint4*)&ri[row * 1024 + 512 + c8];
        uint4 gw = *(const uint4*)&gate[row * DRR + c8];
        const ushort_t* up = (const ushort_t*)&uw;
        const ushort_t* rp = (const ushort_t*)&rw;
        const ushort_t* ip = (const ushort_t*)&iw;
        const ushort_t* gp = (const ushort_t*)&gw;
        ushort_t o[8];
        #pragma unroll
        for (int q = 0; q < 8; ++q) {
            const float rv = sigmoid_f(bf2f(rp[q]));
            const float iv = sigmoid_f(bf2f(ip[q]));
            const float e  = fexp2(a2v[q] * rv);
            const float hv = e * h[q]
                           + sqrtf(fmaxf(0.f, 1.f - e * e)) * (iv * bf2f(up[q]));
            h[q] = hv;
            o[q] = f2bf(hv * bf2f(gp[q]));
        }
        *(uint4*)&u[row * DRR + c8] = *(const uint4*)o;
    }
}

// ---------------------------------------------------------------- small kernels

struct TrArgs { const float* W[12]; };
__global__ void tr_all_k(TrArgs a, ushort_t* __restrict__ wt)
{
    constexpr int KT[12]  = {384,1024,384,384,512,512,512,384,384,1152,384,384};
    constexpr int NTb[12] = {1024,384,512,512,512,512,384,1152,1152,384,384,384};
    constexpr int EOFF[12]= {0,393216,786432,983040,1179648,1441792,1703936,
                             1900544,2342912,2785280,3227648,3375104};
    constexpr int TPRE[13]= {0,384,768,960,1152,1408,1664,1856,2288,2720,3152,3296,3440};
    const int tb = blockIdx.x;
    int s = 0;
    #pragma unroll
    for (int i = 0; i < 12; ++i) if (tb >= TPRE[i+1]) s = i + 1;
    const int rel = tb - TPRE[s];
    const int K = KT[s], N = NTb[s];
    const int ntn = N >> 5;
    const int k0 = (rel / ntn) * 32, n0 = (rel % ntn) * 32;

    __shared__ float ts[32][33];
    const int r = threadIdx.x >> 3, c4 = (threadIdx.x & 7) * 4;
    const float4 v = *(const float4*)&a.W[s][(size_t)(k0 + r) * N + n0 + c4];
    ts[r][c4+0] = v.x; ts[r][c4+1] = v.y; ts[r][c4+2] = v.z; ts[r][c4+3] = v.w;
    __syncthreads();
    ushort_t o4[4];
    #pragma unroll
    for (int q = 0; q < 4; ++q) o4[q] = f2bf(ts[c4 + q][r]);
    *(uint2*)&wt[EOFF[s] + (size_t)(n0 + r) * K + k0 + c4] = *(const uint2*)o4;
}

__global__ void prep_k(const float* __restrict__ rg_bx, const float* __restrict__ rg_by,
                       const float* __restrict__ rg_lam,
                       const float* __restrict__ rg_br, const float* __restrict__ rg_bi,
                       float* __restrict__ bias_xy, float* __restrict__ a2,
                       float* __restrict__ bias_ri)
{
    int i = blockIdx.x * 256 + threadIdx.x;
    if (i < 512) {
        bias_xy[i] = rg_bx[i];
        bias_ri[i] = rg_br[i];
        float lam = rg_lam[i];
        float sp = (lam > 20.f) ? lam : log1pf(expf(lam));
        a2[i] = -8.0f * sp * 1.4426950408889634f;
    } else if (i < 1024) {
        bias_xy[i] = rg_by[i - 512];
        bias_ri[i] = rg_bi[i - 512];
    }
}

__global__ void negm_k(const float* __restrict__ head, const float* __restrict__ pred,
                       ushort_t* __restrict__ negm_h, int b0, int Bc)
{
    int idx = blockIdx.x * 256 + threadIdx.x;        // < Bc*2*384
    int d = idx % DD, rr = idx / DD;
    int j = (rr >= Bc) ? 1 : 0;
    int b = rr - j * Bc;
    size_t off = ((size_t)(KPP + j) * B_TOT + (b0 + b)) * DD + d;
    negm_h[idx] = f2bf(head[off] + pred[off]);
}

__global__ void asmrms_k(const float* __restrict__ init_f,
                         const float* __restrict__ head, const float* __restrict__ pred,
                         const float* __restrict__ w_ap, const float* __restrict__ b_ap,
                         const float* __restrict__ w_an, const float* __restrict__ b_an,
                         const ushort_t* __restrict__ nf, const float* __restrict__ g1,
                         float* __restrict__ x, ushort_t* __restrict__ hb,
                         int b0, int Bc)
{
    const int lb = blockIdx.x, gb = b0 + lb, lane = threadIdx.x;
    float hp[3][6], nv[2][6], iv[6], wap[6], wan[6];
    #pragma unroll
    for (int q = 0; q < 6; ++q) {
        int d = lane + 64 * q;
        wap[q] = w_ap[d]; wan[q] = w_an[d];
        iv[q] = init_f[(size_t)gb * DD + d];
    }
    float lp[3], ln2[2];
    #pragma unroll
    for (int j = 0; j < 3; ++j) {
        float p = 0.f;
        #pragma unroll
        for (int q = 0; q < 6; ++q) {
            int d = lane + 64 * q;
            size_t off = ((size_t)j * B_TOT + gb) * DD + d;
            float v = head[off] + pred[off];
            hp[j][q] = v;
            p += v * wap[q];
        }
        lp[j] = wave_red_sum(p) + b_ap[0];
    }
    #pragma unroll
    for (int j = 0; j < 2; ++j) {
        float p = 0.f;
        #pragma unroll
        for (int q = 0; q < 6; ++q) {
            int d = lane + 64 * q;
            float v = bf2f(nf[((size_t)j * Bc + lb) * DD + d]);
            nv[j][q] = v;
            p += v * wan[q];
        }
        ln2[j] = wave_red_sum(p) + b_an[0];
    }
    float mp = fmaxf(lp[0], fmaxf(lp[1], lp[2]));
    float e0 = expf(lp[0]-mp), e1 = expf(lp[1]-mp), e2 = expf(lp[2]-mp);
    float sp = e0 + e1 + e2;
    float awp[3] = {e0/sp, e1/sp, e2/sp};
    float mn = fmaxf(ln2[0], ln2[1]);
    float f0 = expf(ln2[0]-mn), f1 = expf(ln2[1]-mn);
    float sn = f0 + f1;
    float awn[2] = {f0/sn, f1/sn};

    #pragma unroll
    for (int t = 0; t < SS; ++t) {
        float rowv[6], ss = 0.f;
        #pragma unroll
        for (int q = 0; q < 6; ++q) {
            float v;
            if (t == 0)      v = iv[q];
            else if (t <= 3) v = hp[t-1][q] * awp[t-1];
            else             v = nv[t-4][q] * awn[t-4];
            rowv[q] = v;
            ss += v * v;
        }
        ss = wave_red_sum(ss);
        float sc = rsqrtf(ss / (float)DD + 1e-6f);
        float* xr = x + (size_t)(t * Bc + lb) * DD;
        ushort_t* hr = hb + (size_t)(t * Bc + lb) * DD;
        #pragma unroll
        for (int q = 0; q < 6; ++q) {
            int d = lane + 64 * q;
            xr[d] = rowv[q];
            hr[d] = f2bf(rowv[q] * g1[d] * sc);
        }
    }
}

__global__ void rms_k(const float* __restrict__ x, const float* __restrict__ g,
                      ushort_t* __restrict__ h)
{
    int row  = blockIdx.x * 4 + (threadIdx.x >> 6);
    int lane = threadIdx.x & 63;
    const float* xr = x + (size_t)row * DD;
    float ss = 0.f;
    for (int d = lane; d < DD; d += 64) { float v = xr[d]; ss += v * v; }
    ss = wave_red_sum(ss);
    float sc = rsqrtf(ss / (float)DD + 1e-6f);
    ushort_t* hr = h + (size_t)row * DD;
    for (int d = lane; d < DD; d += 64) hr[d] = f2bf(xr[d] * g[d] * sc);
}

__global__ void wproj_k(const float* __restrict__ fa_wo, const float* __restrict__ fa_wl,
                        float* __restrict__ wproj)
{
    int d = threadIdx.x;  // 384 threads
    float s = 0.f;
    for (int k = 0; k < DD; ++k) s += fa_wo[(size_t)d * DD + k] * fa_wl[k];
    wproj[d] = s;
}

__global__ void final_k(const float* __restrict__ x, const float* __restrict__ lp,
                        const float* __restrict__ fa_bl,
                        float* __restrict__ out, int b0, int Bc)
{
    const int lb = blockIdx.x, gb = b0 + lb, lane = threadIdx.x;
    float lg[SS];
    #pragma unroll
    for (int t = 0; t < SS; ++t) {
        const float* pp = lp + (size_t)(t * Bc + lb) * 6;
        lg[t] = pp[0] + pp[1] + pp[2] + pp[3] + pp[4] + pp[5] + fa_bl[0];
    }
    float m = lg[0];
    #pragma unroll
    for (int t = 1; t < SS; ++t) m = fmaxf(m, lg[t]);
    float e[SS], s = 0.f;
    #pragma unroll
    for (int t = 0; t < SS; ++t) { e[t] = expf(lg[t] - m); s += e[t]; }
    float inv = 1.0f / s;
    #pragma unroll
    for (int q = 0; q < 6; ++q) {
        int d = lane + 64 * q;
        float acc = 0.f;
        #pragma unroll
        for (int t = 0; t < SS; ++t)
            acc += x[(size_t)(t * Bc + lb) * DD + d] * (e[t] * inv);
        out[(size_t)gb * DD + d] = acc * (1.0f / 6.0f);
    }
}

// ---------------------------------------------------------------- launch
extern "C" void kernel_launch(void* const* d_in, const int* in_sizes, int n_in,
                              void* d_out, int out_size, void* d_ws, size_t ws_size,
                              hipStream_t stream)
{
    (void)in_sizes; (void)n_in; (void)out_size;
    const float* init_f  = (const float*)d_in[0];
    const float* head    = (const float*)d_in[1];
    const float* pred    = (const float*)d_in[2];
    const float* w_ap    = (const float*)d_in[3];
    const float* b_ap    = (const float*)d_in[4];
    const float* w_an    = (const float*)d_in[5];
    const float* b_an    = (const float*)d_in[6];
    const float* nt_w1   = (const float*)d_in[7];
    const float* nt_b1   = (const float*)d_in[8];
    const float* nt_w2   = (const float*)d_in[9];
    const float* nt_b2   = (const float*)d_in[10];
    const float* g1      = (const float*)d_in[11];
    const float* rg_wx   = (const float*)d_in[12];
    const float* rg_bx   = (const float*)d_in[13];
    const float* rg_wy   = (const float*)d_in[14];
    const float* rg_by   = (const float*)d_in[15];
    const float* rg_wr   = (const float*)d_in[16];
    const float* rg_br   = (const float*)d_in[17];
    const float* rg_wi   = (const float*)d_in[18];
    const float* rg_bi   = (const float*)d_in[19];
    const float* rg_lam  = (const float*)d_in[20];
    const float* rg_wo   = (const float*)d_in[21];
    const float* rg_bo   = (const float*)d_in[22];
    const float* g2      = (const float*)d_in[23];
    const float* mlp_wg  = (const float*)d_in[24];
    const float* mlp_wv  = (const float*)d_in[25];
    const float* mlp_wo  = (const float*)d_in[26];
    const float* fa_wg   = (const float*)d_in[27];
    const float* fa_wv   = (const float*)d_in[28];
    const float* fa_wo   = (const float*)d_in[29];
    const float* fa_wl   = (const float*)d_in[30];
    const float* fa_bl   = (const float*)d_in[31];
    float* out = (float*)d_out;

    float* ws_f    = (float*)d_ws;
    float* wproj   = ws_f;                 // 512 f32
    float* bias_xy = ws_f + 512;           // 1024
    float* a2      = ws_f + 1536;          // 512
    float* bias_ri = ws_f + 2048;          // 1024
    ushort_t* wt   = (ushort_t*)(ws_f + 3072);

    ushort_t* ntw1T = wt + 0;
    ushort_t* ntw2T = wt + 393216;
    ushort_t* wxyT  = wt + 786432;   // wx rows [0,512), wy rows [512,1024)
    ushort_t* wriT  = wt + 1179648;  // wr rows [0,512), wi rows [512,1024)
    ushort_t* woT   = wt + 1703936;
    ushort_t* mwgT  = wt + 1900544;
    ushort_t* mwvT  = wt + 2342912;
    ushort_t* mwoT  = wt + 2785280;
    ushort_t* fwgT  = wt + 3227648;
    ushort_t* fwvT  = wt + 3375104;  // end 3522560 bf16 = 1761280 f32

    TrArgs ta;
    ta.W[0]=nt_w1; ta.W[1]=nt_w2; ta.W[2]=rg_wx; ta.W[3]=rg_wy;
    ta.W[4]=rg_wr; ta.W[5]=rg_wi; ta.W[6]=rg_wo; ta.W[7]=mlp_wg;
    ta.W[8]=mlp_wv; ta.W[9]=mlp_wo; ta.W[10]=fa_wg; ta.W[11]=fa_wv;
    tr_all_k<<<3440, 256, 0, stream>>>(ta, wt);
    prep_k<<<4, 256, 0, stream>>>(rg_bx, rg_by, rg_lam, rg_br, rg_bi,
                                  bias_xy, a2, bias_ri);
    wproj_k<<<1, DD, 0, stream>>>(fa_wo, fa_wl, wproj);

    const size_t fixed_f32 = 3072 + 1761280;
    const size_t per_b_f32 = 8448;
    int Bc = B_TOT;
    while (Bc > 128 && (fixed_f32 + per_b_f32 * (size_t)Bc) * 4 > ws_size) Bc >>= 1;

    float* arena = ws_f + fixed_f32;

    for (int b0 = 0; b0 < B_TOT; b0 += Bc) {
        const int M  = Bc * SS;
        const int M2 = Bc * KNN;
        float*    xbuf = arena;                                    // [0,2304) live always
        ushort_t* negm = (ushort_t*)(arena + (size_t)2304 * Bc);   // [2304,2688)
        ushort_t* hid  = (ushort_t*)(arena + (size_t)2688 * Bc);   // [2688,3712)
        ushort_t* nf   = (ushort_t*)(arena + (size_t)3712 * Bc);   // [3712,4096)
        ushort_t* hb   = (ushort_t*)(arena + (size_t)4096 * Bc);   // [4096,5248)
        ushort_t* uh   = (ushort_t*)(arena + (size_t)5376 * Bc);   // [5376,6912)
        ushort_t* gth  = (ushort_t*)(arena + (size_t)6912 * Bc);   // [6912,8448)
        ushort_t* ri   = (ushort_t*)(arena + (size_t)2304 * Bc);   // [2304,5376)
        ushort_t* h2   = (ushort_t*)(arena + (size_t)2304 * Bc);   // [2304,3456)
        ushort_t* Th   = (ushort_t*)(arena + (size_t)3456 * Bc);   // [3456,6912)
        ushort_t* xh   = (ushort_t*)(arena + (size_t)6912 * Bc);   // [6912,8064)
        float*    lpb  = arena + (size_t)2304 * Bc;                // [2304,2340)

        // stage 1: neg messages + MLP residual + attention assembly (+rms g1)
        negm_k<<<Bc * 3, 256, 0, stream>>>(head, pred, negm, b0, Bc);
        bgemm<1, false><<<dim3(HH/128, M2/128), 256, 0, stream>>>(
            negm, ntw1T, nt_b1, nullptr, nullptr, hid, nullptr, M2, HH, DD);
        bgemm<4, false><<<dim3(DD/128, M2/128), 256, 0, stream>>>(
            hid, ntw2T, nt_b2, negm, nullptr, nf, nullptr, M2, DD, HH);
        asmrms_k<<<Bc, 64, 0, stream>>>(init_f, head, pred, w_ap, b_ap, w_an, b_an,
                                        nf, g1, xbuf, hb, b0, Bc);

        // Griffin recurrent branch
        bgemm<7, false><<<dim3(1024/128, M/128), 256, 0, stream>>>(
            hb, wxyT, bias_xy, nullptr, nullptr, uh, gth, M, 1024, DD);
        bgemm<0, false><<<dim3(1024/128, M/128), 256, 0, stream>>>(
            uh, wriT, bias_ri, nullptr, nullptr, ri, nullptr, M, 1024, DRR);
        rec_k<<<Bc / 4, 256, 0, stream>>>(uh, gth, ri, a2, Bc);
        bgemm<0, true><<<dim3(DD/128, M/128), 256, 0, stream>>>(
            uh, woT, rg_bo, nullptr, xbuf, nullptr, nullptr, M, DD, DRR);

        // gated-MLP residual branch
        rms_k<<<M / 4, 256, 0, stream>>>(xbuf, g2, h2);
        dual_k<false><<<dim3(DMM/64, M/128), 256, 0, stream>>>(
            h2, mwgT, mwvT, Th, nullptr, nullptr, M, DMM, DD);
        bgemm<0, true><<<dim3(DD/128, M/128), 256, 0, stream>>>(
            Th, mwoT, nullptr, nullptr, xbuf, xh, nullptr, M, DD, DMM);

        // final attention: fused dual-GEMM -> per-row logit partials
        dual_k<true><<<dim3(DD/64, M/128), 256, 0, stream>>>(
            xh, fwgT, fwvT, nullptr, lpb, wproj, M, DD, DD);
        final_k<<<Bc, 64, 0, stream>>>(xbuf, lpb, fa_bl, out, b0, Bc);
    }
}

// Round 12
// 1478.199 us; speedup vs baseline: 1.6401x; 1.6401x over previous
//
#include <hip/hip_runtime.h>
#include <hip/hip_bf16.h>

// Problem constants (from reference)
#define B_TOT 16384
#define DD    384
#define HH    1024
#define DRR   512
#define DMM   1152
#define SS    6     // 1 + KP + KN
#define KPP   3
#define KNN   2

typedef unsigned short ushort_t;
typedef __bf16 bf16x8 __attribute__((ext_vector_type(8)));
typedef float  f32x4  __attribute__((ext_vector_type(4)));

// ---------------------------------------------------------------- helpers
__device__ __forceinline__ float fexp2(float x) { return __builtin_amdgcn_exp2f(x); }
__device__ __forceinline__ float frcp(float x)  { return __builtin_amdgcn_rcpf(x); }
__device__ __forceinline__ float sigmoid_f(float x) {
    return frcp(1.f + fexp2(-1.4426950408889634f * x));
}
__device__ __forceinline__ float gelu_f(float x) {
    float z = 0.7978845608028654f * x * (1.f + 0.044715f * x * x);
    return x * frcp(1.f + fexp2(-2.885390081777927f * z));
}
__device__ __forceinline__ float wave_red_sum(float v) {
    #pragma unroll
    for (int off = 32; off; off >>= 1) v += __shfl_xor(v, off);
    return v;
}
__device__ __forceinline__ ushort_t f2bf(float v) {
    __hip_bfloat16 h = __float2bfloat16(v);
    return *reinterpret_cast<ushort_t*>(&h);
}
__device__ __forceinline__ float bf2f(ushort_t u) {
    unsigned int x = ((unsigned int)u) << 16;
    return __uint_as_float(x);
}
// async global->LDS, 16B per lane
__device__ __forceinline__ void g2l16(const ushort_t* g, ushort_t* l) {
    __builtin_amdgcn_global_load_lds(
        (const __attribute__((address_space(1))) void*)g,
        (__attribute__((address_space(3))) void*)l, 16, 0, 0);
}
// XCD-aware bijective block swizzle
__device__ __forceinline__ void swz_xy(int& bx, int& by) {
    const int nx = gridDim.x;
    const int nwg = nx * gridDim.y;
    const int h = by * nx + bx;
    const int q = nwg >> 3, r = nwg & 7;
    const int xcd = h & 7, lo = h >> 3;
    const int lin = (xcd < r) ? (xcd * (q + 1) + lo)
                              : (r * (q + 1) + (xcd - r) * q + lo);
    bx = lin % nx;
    by = lin / nx;
}

// ---------------------------------------------------------------- MFMA GEMM
// m97 single-buffer structure, 32 KiB LDS -> 4 blocks/CU (round-9 proven).
// K is COMPILE-TIME: NT static -> loop unrolled/pipelined, addresses folded.
template<int EPI, bool ACCUM, int K>
__global__ __launch_bounds__(256, 4)
void bgemm(const ushort_t* __restrict__ A, const ushort_t* __restrict__ WT,
           const float* __restrict__ bias, const ushort_t* __restrict__ X2,
           float* __restrict__ C, ushort_t* __restrict__ Ch, ushort_t* __restrict__ Ch2,
           int M, int N)
{
    __shared__ ushort_t sm[16384];   // 32 KiB

    int bx = blockIdx.x, by = blockIdx.y;
    swz_xy(bx, by);
    const int tid = threadIdx.x;
    const int l = tid & 63, w = tid >> 6;
    const int wr = w >> 1, wc = w & 1;
    const int lr = l & 15, hi = l >> 4;
    const int row0 = by * 128, col0 = bx * 128;

    const int lrw = l >> 3;
    const int lch = (l & 7) ^ (lrw & 7);
    const ushort_t* As[4]; const ushort_t* Bs[4]; int lo_[4];
    #pragma unroll
    for (int i = 0; i < 4; ++i) {
        const int g = w * 4 + i;
        As[i] = A  + (size_t)(row0 + g*8 + lrw) * K + lch * 8;
        Bs[i] = WT + (size_t)(col0 + g*8 + lrw) * K + lch * 8;
        lo_[i] = g * 512;
    }
    const int ko[2] = {(hi*8) ^ ((lr&7)*8), (32 + hi*8) ^ ((lr&7)*8)};

    f32x4 acc[4][4] = {};
    constexpr int NT = K >> 6;

    #pragma unroll
    for (int i = 0; i < 4; ++i) {
        g2l16(As[i], &sm[lo_[i]]);
        g2l16(Bs[i], &sm[8192 + lo_[i]]);
    }
    for (int t = 0; t < NT; ++t) {
        __syncthreads();                       // drains vmcnt: tile t ready
        #pragma unroll
        for (int ks = 0; ks < 2; ++ks) {
            bf16x8 af[4], bfr[4];
            #pragma unroll
            for (int m = 0; m < 4; ++m)
                af[m] = *(const bf16x8*)&sm[(wr*64 + m*16 + lr)*64 + ko[ks]];
            #pragma unroll
            for (int n = 0; n < 4; ++n)
                bfr[n] = *(const bf16x8*)&sm[8192 + (wc*64 + n*16 + lr)*64 + ko[ks]];
            #pragma unroll
            for (int m = 0; m < 4; ++m)
                #pragma unroll
                for (int n = 0; n < 4; ++n)
                    acc[m][n] = __builtin_amdgcn_mfma_f32_16x16x32_bf16(
                        af[m], bfr[n], acc[m][n], 0, 0, 0);
        }
        __syncthreads();                       // all waves done reading LDS
        if (t + 1 < NT) {
            #pragma unroll
            for (int i = 0; i < 4; ++i) {
                g2l16(As[i] + (size_t)(t+1)*64, &sm[lo_[i]]);
                g2l16(Bs[i] + (size_t)(t+1)*64, &sm[8192 + lo_[i]]);
            }
        }
    }

    // epilogue: C/D frag mapping col = l&15, row = (l>>4)*4 + j
    const bool BF = (EPI == 7) || (Ch != nullptr);
    #pragma unroll
    for (int m = 0; m < 4; ++m) {
        #pragma unroll
        for (int n = 0; n < 4; ++n) {
            const int r0 = row0 + wr*64 + m*16 + hi*4;
            const int c  = col0 + wc*64 + n*16 + lr;
            const float bv = bias ? bias[c] : 0.f;
            const int rl0 = wr*64 + m*16 + hi*4;
            const int cl  = wc*64 + n*16 + lr;
            #pragma unroll
            for (int j = 0; j < 4; ++j) {
                const int r = r0 + j;
                float v = acc[m][n][j] + bv;
                if (EPI == 1) v = fmaxf(v, 0.f);
                if (EPI == 4) v = v - bf2f(X2[(size_t)r * N + c]);
                if (ACCUM)    v += C[(size_t)r * N + c];
                if (C) C[(size_t)r * N + c] = v;
                if (BF) {
                    float ov = (EPI == 7 && c >= 512) ? gelu_f(v) : v;
                    const int rl = rl0 + j;
                    sm[rl*128 + ((((cl>>3) ^ (rl & 7))) << 3) + (cl & 7)] = f2bf(ov);
                }
            }
        }
    }
    if (BF) {
        __syncthreads();
        const int er = tid >> 1, ec = (tid & 1) * 64;
        ushort_t* dst; int nn, dc0;
        if (EPI == 7) {
            nn = 512;
            if (col0 < 512) { dst = Ch;  dc0 = col0; }
            else            { dst = Ch2; dc0 = col0 - 512; }
        } else { dst = Ch; nn = N; dc0 = col0; }
        ushort_t* gp = dst + (size_t)(row0 + er) * nn + dc0 + ec;
        #pragma unroll
        for (int qq = 0; qq < 8; ++qq) {
            const int q = (ec >> 3) + qq;
            const uint4 vv = *(const uint4*)&sm[er*128 + ((q ^ (er & 7)) << 3)];
            *(uint4*)(gp + qq*8) = vv;
        }
    }
}

// ---------------------------------------------------------------- dual-B GEMM
// Round-9 structure exactly: single-buffer 32 KiB (A 16K, G 8K, V 8K),
// __launch_bounds__(256,4) -- (256,5) regressed: allocator clamped VGPR to 48
// (< the 64 live accumulators) and spilled to scratch (790 MB FETCH, R11).
// K compile-time (always 384 here, NT=6).
template<bool LOGITS, int K>
__global__ __launch_bounds__(256, 4)
void dual_k(const ushort_t* __restrict__ A, const ushort_t* __restrict__ W1T,
            const ushort_t* __restrict__ W2T, ushort_t* __restrict__ Ch,
            float* __restrict__ LP, const float* __restrict__ wproj,
            int M, int N)
{
    __shared__ ushort_t sm[16384];

    int bx = blockIdx.x, by = blockIdx.y;
    swz_xy(bx, by);
    const int tid = threadIdx.x;
    const int l = tid & 63, w = tid >> 6;
    const int wr = w >> 1, wc = w & 1;
    const int lr = l & 15, hi = l >> 4;
    const int row0 = by * 128, col0 = bx * 64;

    const int lrw = l >> 3;
    const int lch = (l & 7) ^ (lrw & 7);
    const ushort_t* As[4]; int loA[4];
    #pragma unroll
    for (int i = 0; i < 4; ++i) {
        const int g = w * 4 + i;
        As[i] = A + (size_t)(row0 + g*8 + lrw) * K + lch * 8;
        loA[i] = g * 512;
    }
    const ushort_t* Gs[2]; const ushort_t* Vs[2]; int loB[2];
    #pragma unroll
    for (int i = 0; i < 2; ++i) {
        const int g = w * 2 + i;
        Gs[i] = W1T + (size_t)(col0 + g*8 + lrw) * K + lch * 8;
        Vs[i] = W2T + (size_t)(col0 + g*8 + lrw) * K + lch * 8;
        loB[i] = g * 512;
    }
    const int ko[2] = {(hi*8) ^ ((lr&7)*8), (32 + hi*8) ^ ((lr&7)*8)};

    f32x4 ag[4][2] = {}, av[4][2] = {};
    constexpr int NT = K >> 6;

    #pragma unroll
    for (int i = 0; i < 4; ++i) g2l16(As[i], &sm[loA[i]]);
    #pragma unroll
    for (int i = 0; i < 2; ++i) {
        g2l16(Gs[i], &sm[8192  + loB[i]]);
        g2l16(Vs[i], &sm[12288 + loB[i]]);
    }
    for (int t = 0; t < NT; ++t) {
        __syncthreads();
        #pragma unroll
        for (int ks = 0; ks < 2; ++ks) {
            bf16x8 af[4], bg[2], bv[2];
            #pragma unroll
            for (int m = 0; m < 4; ++m)
                af[m] = *(const bf16x8*)&sm[(wr*64 + m*16 + lr)*64 + ko[ks]];
            #pragma unroll
            for (int n = 0; n < 2; ++n) {
                bg[n] = *(const bf16x8*)&sm[8192  + (wc*32 + n*16 + lr)*64 + ko[ks]];
                bv[n] = *(const bf16x8*)&sm[12288 + (wc*32 + n*16 + lr)*64 + ko[ks]];
            }
            #pragma unroll
            for (int m = 0; m < 4; ++m)
                #pragma unroll
                for (int n = 0; n < 2; ++n) {
                    ag[m][n] = __builtin_amdgcn_mfma_f32_16x16x32_bf16(af[m], bg[n], ag[m][n], 0, 0, 0);
                    av[m][n] = __builtin_amdgcn_mfma_f32_16x16x32_bf16(af[m], bv[n], av[m][n], 0, 0, 0);
                }
        }
        __syncthreads();
        if (t + 1 < NT) {
            #pragma unroll
            for (int i = 0; i < 4; ++i)
                g2l16(As[i] + (size_t)(t+1)*64, &sm[loA[i]]);
            #pragma unroll
            for (int i = 0; i < 2; ++i) {
                g2l16(Gs[i] + (size_t)(t+1)*64, &sm[8192  + loB[i]]);
                g2l16(Vs[i] + (size_t)(t+1)*64, &sm[12288 + loB[i]]);
            }
        }
    }

    if (!LOGITS) {
        #pragma unroll
        for (int m = 0; m < 4; ++m)
            #pragma unroll
            for (int n = 0; n < 2; ++n) {
                const int cl = wc*32 + n*16 + lr;
                #pragma unroll
                for (int j = 0; j < 4; ++j) {
                    const int rl = wr*64 + m*16 + hi*4 + j;
                    sm[rl*64 + (((cl>>3) ^ (rl & 7)) << 3) + (cl & 7)] =
                        f2bf(gelu_f(ag[m][n][j]) * av[m][n][j]);
                }
            }
        __syncthreads();
        const int er = tid >> 1, ec = (tid & 1) * 32;
        ushort_t* gp = Ch + (size_t)(row0 + er) * N + col0 + ec;
        #pragma unroll
        for (int qq = 0; qq < 4; ++qq) {
            const int q = (ec >> 3) + qq;
            const uint4 vv = *(const uint4*)&sm[er*64 + ((q ^ (er & 7)) << 3)];
            *(uint4*)(gp + qq*8) = vv;
        }
    } else {
        float wp[2];
        #pragma unroll
        for (int n = 0; n < 2; ++n) wp[n] = wproj[col0 + wc*32 + n*16 + lr];
        float* red = (float*)sm;   // [128][2]
        #pragma unroll
        for (int m = 0; m < 4; ++m) {
            #pragma unroll
            for (int j = 0; j < 4; ++j) {
                float s = 0.f;
                #pragma unroll
                for (int n = 0; n < 2; ++n)
                    s += gelu_f(ag[m][n][j]) * av[m][n][j] * wp[n];
                s += __shfl_xor(s, 1);
                s += __shfl_xor(s, 2);
                s += __shfl_xor(s, 4);
                s += __shfl_xor(s, 8);
                if (lr == 0) red[(wr*64 + m*16 + hi*4 + j) * 2 + wc] = s;
            }
        }
        __syncthreads();
        if (tid < 128)
            LP[(size_t)(row0 + tid) * 6 + bx] = red[tid*2] + red[tid*2 + 1];
    }
}

// ---------------------------------------------------------------- RG-LRU recurrence
__global__ __launch_bounds__(256, 8)
void rec_k(ushort_t* __restrict__ u, const ushort_t* __restrict__ gate,
           const ushort_t* __restrict__ ri, const float* __restrict__ a2,
           int Bc)
{
    const int g = blockIdx.x * 256 + threadIdx.x;   // < Bc*64
    const int b = g >> 6, c8 = (g & 63) << 3;
    float a2v[8];
    *(float4*)&a2v[0] = *(const float4*)&a2[c8];
    *(float4*)&a2v[4] = *(const float4*)&a2[c8 + 4];
    float h[8] = {};
    for (int t = 0; t < SS; ++t) {
        const size_t row = (size_t)t * Bc + b;
        uint4 uw = *(const uint4*)&u[row * DRR + c8];
        uint4 rw = *(const uint4*)&ri[row * 1024 + c8];
        uint4 iw = *(const uint4*)&ri[row * 1024 + 512 + c8];
        uint4 gw = *(const uint4*)&gate[row * DRR + c8];
        const ushort_t* up = (const ushort_t*)&uw;
        const ushort_t* rp = (const ushort_t*)&rw;
        const ushort_t* ip = (const ushort_t*)&iw;
        const ushort_t* gp = (const ushort_t*)&gw;
        ushort_t o[8];
        #pragma unroll
        for (int q = 0; q < 8; ++q) {
            const float rv = sigmoid_f(bf2f(rp[q]));
            const float iv = sigmoid_f(bf2f(ip[q]));
            const float e  = fexp2(a2v[q] * rv);
            const float hv = e * h[q]
                           + sqrtf(fmaxf(0.f, 1.f - e * e)) * (iv * bf2f(up[q]));
            h[q] = hv;
            o[q] = f2bf(hv * bf2f(gp[q]));
        }
        *(uint4*)&u[row * DRR + c8] = *(const uint4*)o;
    }
}

// ---------------------------------------------------------------- small kernels

struct TrArgs { const float* W[12]; };
__global__ void tr_all_k(TrArgs a, ushort_t* __restrict__ wt)
{
    constexpr int KT[12]  = {384,1024,384,384,512,512,512,384,384,1152,384,384};
    constexpr int NTb[12] = {1024,384,512,512,512,512,384,1152,1152,384,384,384};
    constexpr int EOFF[12]= {0,393216,786432,983040,1179648,1441792,1703936,
                             1900544,2342912,2785280,3227648,3375104};
    constexpr int TPRE[13]= {0,384,768,960,1152,1408,1664,1856,2288,2720,3152,3296,3440};
    const int tb = blockIdx.x;
    int s = 0;
    #pragma unroll
    for (int i = 0; i < 12; ++i) if (tb >= TPRE[i+1]) s = i + 1;
    const int rel = tb - TPRE[s];
    const int K = KT[s], N = NTb[s];
    const int ntn = N >> 5;
    const int k0 = (rel / ntn) * 32, n0 = (rel % ntn) * 32;

    __shared__ float ts[32][33];
    const int r = threadIdx.x >> 3, c4 = (threadIdx.x & 7) * 4;
    const float4 v = *(const float4*)&a.W[s][(size_t)(k0 + r) * N + n0 + c4];
    ts[r][c4+0] = v.x; ts[r][c4+1] = v.y; ts[r][c4+2] = v.z; ts[r][c4+3] = v.w;
    __syncthreads();
    ushort_t o4[4];
    #pragma unroll
    for (int q = 0; q < 4; ++q) o4[q] = f2bf(ts[c4 + q][r]);
    *(uint2*)&wt[EOFF[s] + (size_t)(n0 + r) * K + k0 + c4] = *(const uint2*)o4;
}

__global__ void prep_k(const float* __restrict__ rg_bx, const float* __restrict__ rg_by,
                       const float* __restrict__ rg_lam,
                       const float* __restrict__ rg_br, const float* __restrict__ rg_bi,
                       float* __restrict__ bias_xy, float* __restrict__ a2,
                       float* __restrict__ bias_ri)
{
    int i = blockIdx.x * 256 + threadIdx.x;
    if (i < 512) {
        bias_xy[i] = rg_bx[i];
        bias_ri[i] = rg_br[i];
        float lam = rg_lam[i];
        float sp = (lam > 20.f) ? lam : log1pf(expf(lam));
        a2[i] = -8.0f * sp * 1.4426950408889634f;
    } else if (i < 1024) {
        bias_xy[i] = rg_by[i - 512];
        bias_ri[i] = rg_bi[i - 512];
    }
}

__global__ void negm_k(const float* __restrict__ head, const float* __restrict__ pred,
                       ushort_t* __restrict__ negm_h, int b0, int Bc)
{
    int idx = blockIdx.x * 256 + threadIdx.x;        // < Bc*2*384
    int d = idx % DD, rr = idx / DD;
    int j = (rr >= Bc) ? 1 : 0;
    int b = rr - j * Bc;
    size_t off = ((size_t)(KPP + j) * B_TOT + (b0 + b)) * DD + d;
    negm_h[idx] = f2bf(head[off] + pred[off]);
}

__global__ void asmrms_k(const float* __restrict__ init_f,
                         const float* __restrict__ head, const float* __restrict__ pred,
                         const float* __restrict__ w_ap, const float* __restrict__ b_ap,
                         const float* __restrict__ w_an, const float* __restrict__ b_an,
                         const ushort_t* __restrict__ nf, const float* __restrict__ g1,
                         float* __restrict__ x, ushort_t* __restrict__ hb,
                         int b0, int Bc)
{
    const int lb = blockIdx.x, gb = b0 + lb, lane = threadIdx.x;
    float hp[3][6], nv[2][6], iv[6], wap[6], wan[6];
    #pragma unroll
    for (int q = 0; q < 6; ++q) {
        int d = lane + 64 * q;
        wap[q] = w_ap[d]; wan[q] = w_an[d];
        iv[q] = init_f[(size_t)gb * DD + d];
    }
    float lp[3], ln2[2];
    #pragma unroll
    for (int j = 0; j < 3; ++j) {
        float p = 0.f;
        #pragma unroll
        for (int q = 0; q < 6; ++q) {
            int d = lane + 64 * q;
            size_t off = ((size_t)j * B_TOT + gb) * DD + d;
            float v = head[off] + pred[off];
            hp[j][q] = v;
            p += v * wap[q];
        }
        lp[j] = wave_red_sum(p) + b_ap[0];
    }
    #pragma unroll
    for (int j = 0; j < 2; ++j) {
        float p = 0.f;
        #pragma unroll
        for (int q = 0; q < 6; ++q) {
            int d = lane + 64 * q;
            float v = bf2f(nf[((size_t)j * Bc + lb) * DD + d]);
            nv[j][q] = v;
            p += v * wan[q];
        }
        ln2[j] = wave_red_sum(p) + b_an[0];
    }
    float mp = fmaxf(lp[0], fmaxf(lp[1], lp[2]));
    float e0 = expf(lp[0]-mp), e1 = expf(lp[1]-mp), e2 = expf(lp[2]-mp);
    float sp = e0 + e1 + e2;
    float awp[3] = {e0/sp, e1/sp, e2/sp};
    float mn = fmaxf(ln2[0], ln2[1]);
    float f0 = expf(ln2[0]-mn), f1 = expf(ln2[1]-mn);
    float sn = f0 + f1;
    float awn[2] = {f0/sn, f1/sn};

    #pragma unroll
    for (int t = 0; t < SS; ++t) {
        float rowv[6], ss = 0.f;
        #pragma unroll
        for (int q = 0; q < 6; ++q) {
            float v;
            if (t == 0)      v = iv[q];
            else if (t <= 3) v = hp[t-1][q] * awp[t-1];
            else             v = nv[t-4][q] * awn[t-4];
            rowv[q] = v;
            ss += v * v;
        }
        ss = wave_red_sum(ss);
        float sc = rsqrtf(ss / (float)DD + 1e-6f);
        float* xr = x + (size_t)(t * Bc + lb) * DD;
        ushort_t* hr = hb + (size_t)(t * Bc + lb) * DD;
        #pragma unroll
        for (int q = 0; q < 6; ++q) {
            int d = lane + 64 * q;
            xr[d] = rowv[q];
            hr[d] = f2bf(rowv[q] * g1[d] * sc);
        }
    }
}

__global__ void rms_k(const float* __restrict__ x, const float* __restrict__ g,
                      ushort_t* __restrict__ h)
{
    int row  = blockIdx.x * 4 + (threadIdx.x >> 6);
    int lane = threadIdx.x & 63;
    const float* xr = x + (size_t)row * DD;
    float ss = 0.f;
    for (int d = lane; d < DD; d += 64) { float v = xr[d]; ss += v * v; }
    ss = wave_red_sum(ss);
    float sc = rsqrtf(ss / (float)DD + 1e-6f);
    ushort_t* hr = h + (size_t)row * DD;
    for (int d = lane; d < DD; d += 64) hr[d] = f2bf(xr[d] * g[d] * sc);
}

__global__ void wproj_k(const float* __restrict__ fa_wo, const float* __restrict__ fa_wl,
                        float* __restrict__ wproj)
{
    int d = threadIdx.x;  // 384 threads
    float s = 0.f;
    for (int k = 0; k < DD; ++k) s += fa_wo[(size_t)d * DD + k] * fa_wl[k];
    wproj[d] = s;
}

__global__ void final_k(const float* __restrict__ x, const float* __restrict__ lp,
                        const float* __restrict__ fa_bl,
                        float* __restrict__ out, int b0, int Bc)
{
    const int lb = blockIdx.x, gb = b0 + lb, lane = threadIdx.x;
    float lg[SS];
    #pragma unroll
    for (int t = 0; t < SS; ++t) {
        const float* pp = lp + (size_t)(t * Bc + lb) * 6;
        lg[t] = pp[0] + pp[1] + pp[2] + pp[3] + pp[4] + pp[5] + fa_bl[0];
    }
    float m = lg[0];
    #pragma unroll
    for (int t = 1; t < SS; ++t) m = fmaxf(m, lg[t]);
    float e[SS], s = 0.f;
    #pragma unroll
    for (int t = 0; t < SS; ++t) { e[t] = expf(lg[t] - m); s += e[t]; }
    float inv = 1.0f / s;
    #pragma unroll
    for (int q = 0; q < 6; ++q) {
        int d = lane + 64 * q;
        float acc = 0.f;
        #pragma unroll
        for (int t = 0; t < SS; ++t)
            acc += x[(size_t)(t * Bc + lb) * DD + d] * (e[t] * inv);
        out[(size_t)gb * DD + d] = acc * (1.0f / 6.0f);
    }
}

// ---------------------------------------------------------------- launch
extern "C" void kernel_launch(void* const* d_in, const int* in_sizes, int n_in,
                              void* d_out, int out_size, void* d_ws, size_t ws_size,
                              hipStream_t stream)
{
    (void)in_sizes; (void)n_in; (void)out_size;
    const float* init_f  = (const float*)d_in[0];
    const float* head    = (const float*)d_in[1];
    const float* pred    = (const float*)d_in[2];
    const float* w_ap    = (const float*)d_in[3];
    const float* b_ap    = (const float*)d_in[4];
    const float* w_an    = (const float*)d_in[5];
    const float* b_an    = (const float*)d_in[6];
    const float* nt_w1   = (const float*)d_in[7];
    const float* nt_b1   = (const float*)d_in[8];
    const float* nt_w2   = (const float*)d_in[9];
    const float* nt_b2   = (const float*)d_in[10];
    const float* g1      = (const float*)d_in[11];
    const float* rg_wx   = (const float*)d_in[12];
    const float* rg_bx   = (const float*)d_in[13];
    const float* rg_wy   = (const float*)d_in[14];
    const float* rg_by   = (const float*)d_in[15];
    const float* rg_wr   = (const float*)d_in[16];
    const float* rg_br   = (const float*)d_in[17];
    const float* rg_wi   = (const float*)d_in[18];
    const float* rg_bi   = (const float*)d_in[19];
    const float* rg_lam  = (const float*)d_in[20];
    const float* rg_wo   = (const float*)d_in[21];
    const float* rg_bo   = (const float*)d_in[22];
    const float* g2      = (const float*)d_in[23];
    const float* mlp_wg  = (const float*)d_in[24];
    const float* mlp_wv  = (const float*)d_in[25];
    const float* mlp_wo  = (const float*)d_in[26];
    const float* fa_wg   = (const float*)d_in[27];
    const float* fa_wv   = (const float*)d_in[28];
    const float* fa_wo   = (const float*)d_in[29];
    const float* fa_wl   = (const float*)d_in[30];
    const float* fa_bl   = (const float*)d_in[31];
    float* out = (float*)d_out;

    float* ws_f    = (float*)d_ws;
    float* wproj   = ws_f;                 // 512 f32
    float* bias_xy = ws_f + 512;           // 1024
    float* a2      = ws_f + 1536;          // 512
    float* bias_ri = ws_f + 2048;          // 1024
    ushort_t* wt   = (ushort_t*)(ws_f + 3072);

    ushort_t* ntw1T = wt + 0;
    ushort_t* ntw2T = wt + 393216;
    ushort_t* wxyT  = wt + 786432;   // wx rows [0,512), wy rows [512,1024)
    ushort_t* wriT  = wt + 1179648;  // wr rows [0,512), wi rows [512,1024)
    ushort_t* woT   = wt + 1703936;
    ushort_t* mwgT  = wt + 1900544;
    ushort_t* mwvT  = wt + 2342912;
    ushort_t* mwoT  = wt + 2785280;
    ushort_t* fwgT  = wt + 3227648;
    ushort_t* fwvT  = wt + 3375104;  // end 3522560 bf16 = 1761280 f32

    TrArgs ta;
    ta.W[0]=nt_w1; ta.W[1]=nt_w2; ta.W[2]=rg_wx; ta.W[3]=rg_wy;
    ta.W[4]=rg_wr; ta.W[5]=rg_wi; ta.W[6]=rg_wo; ta.W[7]=mlp_wg;
    ta.W[8]=mlp_wv; ta.W[9]=mlp_wo; ta.W[10]=fa_wg; ta.W[11]=fa_wv;
    tr_all_k<<<3440, 256, 0, stream>>>(ta, wt);
    prep_k<<<4, 256, 0, stream>>>(rg_bx, rg_by, rg_lam, rg_br, rg_bi,
                                  bias_xy, a2, bias_ri);
    wproj_k<<<1, DD, 0, stream>>>(fa_wo, fa_wl, wproj);

    const size_t fixed_f32 = 3072 + 1761280;
    const size_t per_b_f32 = 8448;
    int Bc = B_TOT;
    while (Bc > 128 && (fixed_f32 + per_b_f32 * (size_t)Bc) * 4 > ws_size) Bc >>= 1;

    float* arena = ws_f + fixed_f32;

    for (int b0 = 0; b0 < B_TOT; b0 += Bc) {
        const int M  = Bc * SS;
        const int M2 = Bc * KNN;
        float*    xbuf = arena;                                    // [0,2304) live always
        ushort_t* negm = (ushort_t*)(arena + (size_t)2304 * Bc);   // [2304,2688)
        ushort_t* hid  = (ushort_t*)(arena + (size_t)2688 * Bc);   // [2688,3712)
        ushort_t* nf   = (ushort_t*)(arena + (size_t)3712 * Bc);   // [3712,4096)
        ushort_t* hb   = (ushort_t*)(arena + (size_t)4096 * Bc);   // [4096,5248)
        ushort_t* uh   = (ushort_t*)(arena + (size_t)5376 * Bc);   // [5376,6912)
        ushort_t* gth  = (ushort_t*)(arena + (size_t)6912 * Bc);   // [6912,8448)
        ushort_t* ri   = (ushort_t*)(arena + (size_t)2304 * Bc);   // [2304,5376)
        ushort_t* h2   = (ushort_t*)(arena + (size_t)2304 * Bc);   // [2304,3456)
        ushort_t* Th   = (ushort_t*)(arena + (size_t)3456 * Bc);   // [3456,6912)
        ushort_t* xh   = (ushort_t*)(arena + (size_t)6912 * Bc);   // [6912,8064)
        float*    lpb  = arena + (size_t)2304 * Bc;                // [2304,2340)

        // stage 1: neg messages + MLP residual + attention assembly (+rms g1)
        negm_k<<<Bc * 3, 256, 0, stream>>>(head, pred, negm, b0, Bc);
        bgemm<1, false, DD><<<dim3(HH/128, M2/128), 256, 0, stream>>>(
            negm, ntw1T, nt_b1, nullptr, nullptr, hid, nullptr, M2, HH);
        bgemm<4, false, HH><<<dim3(DD/128, M2/128), 256, 0, stream>>>(
            hid, ntw2T, nt_b2, negm, nullptr, nf, nullptr, M2, DD);
        asmrms_k<<<Bc, 64, 0, stream>>>(init_f, head, pred, w_ap, b_ap, w_an, b_an,
                                        nf, g1, xbuf, hb, b0, Bc);

        // Griffin recurrent branch
        bgemm<7, false, DD><<<dim3(1024/128, M/128), 256, 0, stream>>>(
            hb, wxyT, bias_xy, nullptr, nullptr, uh, gth, M, 1024);
        bgemm<0, false, DRR><<<dim3(1024/128, M/128), 256, 0, stream>>>(
            uh, wriT, bias_ri, nullptr, nullptr, ri, nullptr, M, 1024);
        rec_k<<<Bc / 4, 256, 0, stream>>>(uh, gth, ri, a2, Bc);
        bgemm<0, true, DRR><<<dim3(DD/128, M/128), 256, 0, stream>>>(
            uh, woT, rg_bo, nullptr, xbuf, nullptr, nullptr, M, DD);

        // gated-MLP residual branch
        rms_k<<<M / 4, 256, 0, stream>>>(xbuf, g2, h2);
        dual_k<false, DD><<<dim3(DMM/64, M/128), 256, 0, stream>>>(
            h2, mwgT, mwvT, Th, nullptr, nullptr, M, DMM);
        bgemm<0, true, DMM><<<dim3(DD/128, M/128), 256, 0, stream>>>(
            Th, mwoT, nullptr, nullptr, xbuf, xh, nullptr, M, DD);

        // final attention: fused dual-GEMM -> per-row logit partials
        dual_k<true, DD><<<dim3(DD/64, M/128), 256, 0, stream>>>(
            xh, fwgT, fwvT, nullptr, lpb, wproj, M, DD);
        final_k<<<Bc, 64, 0, stream>>>(xbuf, lpb, fa_bl, out, b0, Bc);
    }
}